// Round 1
// baseline (1751.038 us; speedup 1.0000x reference)
//
#include <hip/hip_runtime.h>

#define B_   4
#define T_   14
#define N_   196
#define D_   768
#define NH   12
#define HD   64
#define LL   256
#define FF_  3072
#define IMG  224
#define CHW  (IMG*IMG)   // 50176
#define BN   (B_*N_)     // 784

// ---------------------------------------------------------------------------
// K0: q[b,n,c] = mean over the 16x16 spatial block (t1,t2) of channel c
// ---------------------------------------------------------------------------
__global__ __launch_bounds__(256) void pool_kernel(const float* __restrict__ x,
                                                   float* __restrict__ q) {
    int blk = blockIdx.x;
    int b = blk / N_, n = blk % N_;
    int t1 = n / T_, t2 = n % T_;
    const float* xb = x + (size_t)b * D_ * CHW + (size_t)(t1 * 16) * IMG + t2 * 16;
    float* qb = q + (size_t)blk * D_;

    int tid = threadIdx.x;
    int w = tid >> 6, lane = tid & 63;
    int g1 = lane >> 2, g2b = lane & 3;           // 4 lanes per 16-float row

    for (int c = w; c < D_; c += 4) {
        const float* p = xb + (size_t)c * CHW + g1 * IMG + g2b * 4;
        float4 v = *reinterpret_cast<const float4*>(p);
        float s = v.x + v.y + v.z + v.w;
        #pragma unroll
        for (int off = 32; off > 0; off >>= 1) s += __shfl_xor(s, off);
        if (lane == 0) qb[c] = s * (1.0f / 256.0f);
    }
}

// ---------------------------------------------------------------------------
// Generic fp32 tiled GEMM: C[m][n] = act( sum_k A[m][k]*W(k,n) + bias[n] )
//   TRANSW=1: W(k,n) = W[n*ldw + k]  (A @ W^T, W row-major N x K)
//   TRANSW=0: W(k,n) = W[k*ldw + n]  (A @ W,   W row-major K x N)
//   ACT=1: silu
// grid.z batches (per-head) via explicit z-strides.
// Requires: N % 64 == 0, K % 16 == 0. M guarded.
// ---------------------------------------------------------------------------
template <int TRANSW, int ACT>
__global__ __launch_bounds__(256) void gemm_kernel(
    const float* __restrict__ A, const float* __restrict__ W,
    const float* __restrict__ bias, float* __restrict__ C,
    int M, int N, int K, int lda, int ldw, int ldc,
    long azs, long wzs, long czs, int bzs) {

    A += (long)blockIdx.z * azs;
    W += (long)blockIdx.z * wzs;
    C += (long)blockIdx.z * czs;
    if (bias) bias += (long)blockIdx.z * bzs;

    __shared__ float As[16][68];
    __shared__ float Ws[16][68];

    int tid = threadIdx.x;
    int m0 = blockIdx.x * 64, n0 = blockIdx.y * 64;
    int tx = tid & 15, ty = tid >> 4;

    float acc[4][4] = {};

    for (int k0 = 0; k0 < K; k0 += 16) {
        // ---- stage A tile (64 m x 16 k), transposed to As[k][m]
        {
            int m = tid >> 2;
            int kk = (tid & 3) * 4;
            int gm = m0 + m;
            float4 a = make_float4(0.f, 0.f, 0.f, 0.f);
            if (gm < M) a = *reinterpret_cast<const float4*>(&A[(size_t)gm * lda + k0 + kk]);
            As[kk + 0][m] = a.x; As[kk + 1][m] = a.y;
            As[kk + 2][m] = a.z; As[kk + 3][m] = a.w;
        }
        // ---- stage W tile to Ws[k][n]
        if (TRANSW) {
            int nn = tid >> 2;
            int kk = (tid & 3) * 4;
            float4 v = *reinterpret_cast<const float4*>(&W[(size_t)(n0 + nn) * ldw + k0 + kk]);
            Ws[kk + 0][nn] = v.x; Ws[kk + 1][nn] = v.y;
            Ws[kk + 2][nn] = v.z; Ws[kk + 3][nn] = v.w;
        } else {
            int kk = tid >> 4;
            int nn = (tid & 15) * 4;
            float4 v = *reinterpret_cast<const float4*>(&W[(size_t)(k0 + kk) * ldw + n0 + nn]);
            Ws[kk][nn + 0] = v.x; Ws[kk][nn + 1] = v.y;
            Ws[kk][nn + 2] = v.z; Ws[kk][nn + 3] = v.w;
        }
        __syncthreads();

        #pragma unroll
        for (int kk = 0; kk < 16; ++kk) {
            float4 a = *reinterpret_cast<const float4*>(&As[kk][ty * 4]);
            float4 b = *reinterpret_cast<const float4*>(&Ws[kk][tx * 4]);
            acc[0][0] += a.x * b.x; acc[0][1] += a.x * b.y; acc[0][2] += a.x * b.z; acc[0][3] += a.x * b.w;
            acc[1][0] += a.y * b.x; acc[1][1] += a.y * b.y; acc[1][2] += a.y * b.z; acc[1][3] += a.y * b.w;
            acc[2][0] += a.z * b.x; acc[2][1] += a.z * b.y; acc[2][2] += a.z * b.z; acc[2][3] += a.z * b.w;
            acc[3][0] += a.w * b.x; acc[3][1] += a.w * b.y; acc[3][2] += a.w * b.z; acc[3][3] += a.w * b.w;
        }
        __syncthreads();
    }

    float4 bv = make_float4(0.f, 0.f, 0.f, 0.f);
    if (bias) bv = *reinterpret_cast<const float4*>(&bias[n0 + tx * 4]);

    #pragma unroll
    for (int i = 0; i < 4; ++i) {
        int gm = m0 + ty * 4 + i;
        if (gm >= M) continue;
        float4 o;
        o.x = acc[i][0] + bv.x; o.y = acc[i][1] + bv.y;
        o.z = acc[i][2] + bv.z; o.w = acc[i][3] + bv.w;
        if (ACT) {
            o.x = o.x / (1.f + __expf(-o.x));
            o.y = o.y / (1.f + __expf(-o.y));
            o.z = o.z / (1.f + __expf(-o.z));
            o.w = o.w / (1.f + __expf(-o.w));
        }
        *reinterpret_cast<float4*>(&C[(size_t)gm * ldc + n0 + tx * 4]) = o;
    }
}

// ---------------------------------------------------------------------------
// K2: fused attention core, one block per (b,n).
//  pass1: scores[h][l] = sum_cc qk[h][cc] * KV[l][cc]
//  softmax over l
//  pass2: wkv[h][cc] = (1/sum[h]) * sum_l p[h][l] * KV[l][cc]
//  KV[l][co*256+g1*16+g2] = x[b, 3l+co, t1*16+g1, t2*16+g2]
// ---------------------------------------------------------------------------
__global__ __launch_bounds__(512) void attn_kernel(const float* __restrict__ x,
                                                   const float* __restrict__ qk,
                                                   float* __restrict__ wkv) {
    int blk = blockIdx.x;
    int b = blk / N_, n = blk % N_;
    int t1 = n / T_, t2 = n % T_;
    const float* xb = x + (size_t)b * D_ * CHW + (size_t)(t1 * 16) * IMG + t2 * 16;
    const float* qkb = qk + (size_t)blk * (NH * D_);
    float* wkvb = wkv + (size_t)blk * (NH * D_);

    __shared__ float qk_s[NH * D_];     // 36 KB; reused as wkv staging in pass 2
    __shared__ float p_s[NH][LL];       // 12 KB
    __shared__ float p2_s[NH][LL];      // 12 KB
    __shared__ float invsum_s[NH];

    int tid = threadIdx.x;
    int w = tid >> 6, lane = tid & 63;

    for (int i = tid; i < NH * D_ / 4; i += 512)
        reinterpret_cast<float4*>(qk_s)[i] = reinterpret_cast<const float4*>(qkb)[i];
    __syncthreads();

    // ---------------- pass 1: scores ----------------
    {
        int l = (w & 3) * 64 + lane;        // lane owns one l
        int ch = w >> 2;                    // g1 half: rows [ch*8, ch*8+8)
        float acc[NH];
        #pragma unroll
        for (int h = 0; h < NH; ++h) acc[h] = 0.f;
        const float* xl = xb + (size_t)(3 * l) * CHW;

        for (int co = 0; co < 3; ++co) {
            const float* xc = xl + (size_t)co * CHW;
            for (int g1 = ch * 8; g1 < ch * 8 + 8; ++g1) {
                const float* row = xc + g1 * IMG;
                #pragma unroll
                for (int g2b = 0; g2b < 4; ++g2b) {
                    float4 kv = *reinterpret_cast<const float4*>(row + g2b * 4);
                    int cc = co * 256 + g1 * 16 + g2b * 4;
                    #pragma unroll
                    for (int h = 0; h < NH; ++h) {
                        float4 qv = *reinterpret_cast<const float4*>(&qk_s[h * D_ + cc]);
                        acc[h] += qv.x * kv.x + qv.y * kv.y + qv.z * kv.z + qv.w * kv.w;
                    }
                }
            }
        }
        float* dst = ch ? &p2_s[0][0] : &p_s[0][0];
        #pragma unroll
        for (int h = 0; h < NH; ++h) dst[h * LL + l] = acc[h];
    }
    __syncthreads();

    // ---------------- softmax per head ----------------
    const float scale = 0.125f;   // 1/sqrt(64)
    for (int h = w; h < NH; h += 8) {
        float v[4];
        float mx = -1e30f;
        #pragma unroll
        for (int j = 0; j < 4; ++j) {
            int l = lane + 64 * j;
            v[j] = (p_s[h][l] + p2_s[h][l]) * scale;
            mx = fmaxf(mx, v[j]);
        }
        #pragma unroll
        for (int off = 32; off > 0; off >>= 1) mx = fmaxf(mx, __shfl_xor(mx, off));
        float sum = 0.f;
        #pragma unroll
        for (int j = 0; j < 4; ++j) { v[j] = __expf(v[j] - mx); sum += v[j]; }
        #pragma unroll
        for (int off = 32; off > 0; off >>= 1) sum += __shfl_xor(sum, off);
        #pragma unroll
        for (int j = 0; j < 4; ++j) p_s[h][lane + 64 * j] = v[j];
        if (lane == 0) invsum_s[h] = 1.0f / sum;
    }
    __syncthreads();

    // ---------------- pass 2: wkv ----------------
    {
        int hg = w & 3;     // heads hg*3 .. hg*3+2
        int r = w >> 2;     // l range [r*128, r*128+128)
        float4 acc[3][3];
        #pragma unroll
        for (int hh = 0; hh < 3; ++hh)
            #pragma unroll
            for (int f = 0; f < 3; ++f) acc[hh][f] = make_float4(0.f, 0.f, 0.f, 0.f);

        int g1 = lane >> 2, g2b = lane & 3;   // lane -> spatial slot within each co
        for (int l = r * 128; l < r * 128 + 128; ++l) {
            const float* xl = xb + (size_t)(3 * l) * CHW + g1 * IMG + g2b * 4;
            float p0 = p_s[hg * 3 + 0][l];
            float p1 = p_s[hg * 3 + 1][l];
            float p2v = p_s[hg * 3 + 2][l];
            #pragma unroll
            for (int f = 0; f < 3; ++f) {
                float4 kv = *reinterpret_cast<const float4*>(xl + (size_t)f * CHW);
                acc[0][f].x += p0 * kv.x;  acc[0][f].y += p0 * kv.y;
                acc[0][f].z += p0 * kv.z;  acc[0][f].w += p0 * kv.w;
                acc[1][f].x += p1 * kv.x;  acc[1][f].y += p1 * kv.y;
                acc[1][f].z += p1 * kv.z;  acc[1][f].w += p1 * kv.w;
                acc[2][f].x += p2v * kv.x; acc[2][f].y += p2v * kv.y;
                acc[2][f].z += p2v * kv.z; acc[2][f].w += p2v * kv.w;
            }
        }

        float* stg = qk_s;  // reuse (qk no longer needed)
        int slot = lane * 4;                  // cc base within each (co) block of 256
        if (r == 0) {
            #pragma unroll
            for (int hh = 0; hh < 3; ++hh)
                #pragma unroll
                for (int f = 0; f < 3; ++f)
                    *reinterpret_cast<float4*>(&stg[(hg * 3 + hh) * D_ + f * 256 + slot]) = acc[hh][f];
        }
        __syncthreads();
        if (r == 1) {
            #pragma unroll
            for (int hh = 0; hh < 3; ++hh) {
                float inv = invsum_s[hg * 3 + hh];
                #pragma unroll
                for (int f = 0; f < 3; ++f) {
                    float4 o = *reinterpret_cast<float4*>(&stg[(hg * 3 + hh) * D_ + f * 256 + slot]);
                    float4 s;
                    s.x = (acc[hh][f].x + o.x) * inv;
                    s.y = (acc[hh][f].y + o.y) * inv;
                    s.z = (acc[hh][f].z + o.z) * inv;
                    s.w = (acc[hh][f].w + o.w) * inv;
                    *reinterpret_cast<float4*>(&wkvb[(hg * 3 + hh) * D_ + f * 256 + slot]) = s;
                }
            }
        }
    }
}

// ---------------------------------------------------------------------------
extern "C" void kernel_launch(void* const* d_in, const int* in_sizes, int n_in,
                              void* d_out, int out_size, void* d_ws, size_t ws_size,
                              hipStream_t stream) {
    const float* x     = (const float*)d_in[0];
    const float* w_in  = (const float*)d_in[1];
    const float* b_in  = (const float*)d_in[2];
    const float* w_out = (const float*)d_in[3];
    const float* b_out = (const float*)d_in[4];
    const float* w_fc1 = (const float*)d_in[5];
    const float* b_fc1 = (const float*)d_in[6];
    const float* w_fc2 = (const float*)d_in[7];
    const float* b_fc2 = (const float*)d_in[8];
    float* y = (float*)d_out;

    float* ws   = (float*)d_ws;
    float* q    = ws;                       // 784*768
    float* qp   = q    + (size_t)BN * D_;   // 784*768
    float* qkb  = qp   + (size_t)BN * D_;   // 784*9216
    float* wkv  = qkb  + (size_t)BN * NH * D_;  // 784*9216
    float* ctx  = wkv  + (size_t)BN * NH * D_;  // 784*768
    float* aout = ctx  + (size_t)BN * D_;   // 784*768
    float* h1   = aout + (size_t)BN * D_;   // 784*3072

    const float* wq = w_in;
    const float* wk = w_in + (size_t)D_ * D_;
    const float* wv = w_in + (size_t)2 * D_ * D_;
    const float* bq = b_in;
    const float* bv = b_in + 2 * D_;

    // K0: pooled q
    pool_kernel<<<dim3(BN), dim3(256), 0, stream>>>(x, q);

    // K1a: qp = q @ wq^T + bq          (784 x 768, K=768)
    gemm_kernel<1, 0><<<dim3(13, 12, 1), dim3(256), 0, stream>>>(
        q, wq, bq, qp, BN, D_, D_, D_, D_, D_, 0, 0, 0, 0);

    // K1b: per-head qk = qp_head @ wk_head   (784 x 768, K=64, 12 heads)
    gemm_kernel<0, 0><<<dim3(13, 12, NH), dim3(256), 0, stream>>>(
        qp, wk, nullptr, qkb, BN, D_, HD, D_, D_, NH * D_,
        (long)HD, (long)HD * D_, (long)D_, 0);

    // K2: fused attention -> wkv
    attn_kernel<<<dim3(BN), dim3(512), 0, stream>>>(x, qkb, wkv);

    // K3a: per-head ctx = wkv_head @ wv_head^T + bv_head  (784 x 64, K=768)
    gemm_kernel<1, 0><<<dim3(13, 1, NH), dim3(256), 0, stream>>>(
        wkv, wv, bv, ctx, BN, HD, D_, NH * D_, D_, D_,
        (long)D_, (long)HD * D_, (long)HD, HD);

    // K3b: aout = ctx @ w_out^T + b_out    (784 x 768, K=768)
    gemm_kernel<1, 0><<<dim3(13, 12, 1), dim3(256), 0, stream>>>(
        ctx, w_out, b_out, aout, BN, D_, D_, D_, D_, D_, 0, 0, 0, 0);

    // K4a: h1 = silu(aout @ w_fc1^T + b_fc1)   (784 x 3072, K=768)
    gemm_kernel<1, 1><<<dim3(13, 48, 1), dim3(256), 0, stream>>>(
        aout, w_fc1, b_fc1, h1, BN, FF_, D_, D_, D_, FF_, 0, 0, 0, 0);

    // K4b: y = h1 @ w_fc2^T + b_fc2        (784 x 768, K=3072)
    gemm_kernel<1, 0><<<dim3(13, 12, 1), dim3(256), 0, stream>>>(
        h1, w_fc2, b_fc2, y, BN, D_, FF_, FF_, FF_, D_, 0, 0, 0, 0);
}

// Round 2
// 1492.894 us; speedup vs baseline: 1.1729x; 1.1729x over previous
//
#include <hip/hip_runtime.h>

#define B_   4
#define T_   14
#define N_   196
#define D_   768
#define NH   12
#define HD   64
#define LL   256
#define LT   64
#define FF_  3072
#define IMG  224
#define CHW  (IMG*IMG)   // 50176
#define BN   (B_*N_)     // 784

// ---------------------------------------------------------------------------
// K0: pooled q. Block = (b, t1, channel-slice of 48). Waves read full 896B
// contiguous image rows (56 lanes x float4); per-t2 reduce via 2 shfls.
// ---------------------------------------------------------------------------
__global__ __launch_bounds__(256) void pool_kernel(const float* __restrict__ x,
                                                   float* __restrict__ q) {
    int blk = blockIdx.x;                 // B * T_ * 16
    int cs = blk & 15;
    int bt = blk >> 4;
    int t1 = bt % T_, b = bt / T_;
    int tid = threadIdx.x;
    int w = tid >> 6, lane = tid & 63;
    bool act = lane < 56;
    int t2 = lane >> 2;

    const float* xb = x + (size_t)b * D_ * CHW + (size_t)(t1 * 16) * IMG;

    #pragma unroll 2
    for (int i = 0; i < 12; ++i) {
        int c = cs * 48 + w * 12 + i;
        const float* xc = xb + (size_t)c * CHW;
        float acc = 0.f;
        for (int g1 = 0; g1 < 16; ++g1) {
            float s = 0.f;
            if (act) {
                float4 v = *reinterpret_cast<const float4*>(xc + g1 * IMG + lane * 4);
                s = v.x + v.y + v.z + v.w;
            }
            s += __shfl_xor(s, 1);
            s += __shfl_xor(s, 2);
            acc += s;
        }
        if (act && (lane & 3) == 0)
            q[((size_t)b * N_ + t1 * T_ + t2) * D_ + c] = acc * (1.0f / 256.0f);
    }
}

// ---------------------------------------------------------------------------
// fp32 tiled GEMM with optional split-K.
//   TRANSW=1: W(k,n)=W[n*ldw+k];  TRANSW=0: W(k,n)=W[k*ldw+n]
//   KS==1: C[zb*czs + m*ldc + n] = act(acc + bias)
//   KS>1 : Cpart[((zb*KS+ks)*M + m)*N + n] = acc   (raw partial)
// grid.z = Z * KS.
// ---------------------------------------------------------------------------
template <int TRANSW, int ACT>
__global__ __launch_bounds__(256) void gemm_kernel(
    const float* __restrict__ A, const float* __restrict__ W,
    const float* __restrict__ bias, float* __restrict__ C,
    float* __restrict__ Cpart,
    int M, int N, int K, int lda, int ldw, int ldc,
    long azs, long wzs, long czs, int bzs, int KS) {

    int gz = blockIdx.z;
    int ks = gz % KS, zb = gz / KS;
    A += (long)zb * azs;
    W += (long)zb * wzs;
    if (bias) bias += (long)zb * bzs;

    int kbeg = ks * (K / KS);
    int kend = kbeg + K / KS;

    __shared__ float As[16][68];
    __shared__ float Ws[16][68];

    int tid = threadIdx.x;
    int m0 = blockIdx.x * 64, n0 = blockIdx.y * 64;
    int tx = tid & 15, ty = tid >> 4;

    float acc[4][4] = {};

    for (int k0 = kbeg; k0 < kend; k0 += 16) {
        {
            int m = tid >> 2;
            int kk = (tid & 3) * 4;
            int gm = m0 + m;
            float4 a = make_float4(0.f, 0.f, 0.f, 0.f);
            if (gm < M) a = *reinterpret_cast<const float4*>(&A[(size_t)gm * lda + k0 + kk]);
            As[kk + 0][m] = a.x; As[kk + 1][m] = a.y;
            As[kk + 2][m] = a.z; As[kk + 3][m] = a.w;
        }
        if (TRANSW) {
            int nn = tid >> 2;
            int kk = (tid & 3) * 4;
            float4 v = *reinterpret_cast<const float4*>(&W[(size_t)(n0 + nn) * ldw + k0 + kk]);
            Ws[kk + 0][nn] = v.x; Ws[kk + 1][nn] = v.y;
            Ws[kk + 2][nn] = v.z; Ws[kk + 3][nn] = v.w;
        } else {
            int kk = tid >> 4;
            int nn = (tid & 15) * 4;
            float4 v = *reinterpret_cast<const float4*>(&W[(size_t)(k0 + kk) * ldw + n0 + nn]);
            Ws[kk][nn + 0] = v.x; Ws[kk][nn + 1] = v.y;
            Ws[kk][nn + 2] = v.z; Ws[kk][nn + 3] = v.w;
        }
        __syncthreads();

        #pragma unroll
        for (int kk = 0; kk < 16; ++kk) {
            float4 a = *reinterpret_cast<const float4*>(&As[kk][ty * 4]);
            float4 b = *reinterpret_cast<const float4*>(&Ws[kk][tx * 4]);
            acc[0][0] += a.x * b.x; acc[0][1] += a.x * b.y; acc[0][2] += a.x * b.z; acc[0][3] += a.x * b.w;
            acc[1][0] += a.y * b.x; acc[1][1] += a.y * b.y; acc[1][2] += a.y * b.z; acc[1][3] += a.y * b.w;
            acc[2][0] += a.z * b.x; acc[2][1] += a.z * b.y; acc[2][2] += a.z * b.z; acc[2][3] += a.z * b.w;
            acc[3][0] += a.w * b.x; acc[3][1] += a.w * b.y; acc[3][2] += a.w * b.z; acc[3][3] += a.w * b.w;
        }
        __syncthreads();
    }

    if (KS == 1) {
        float4 bv = make_float4(0.f, 0.f, 0.f, 0.f);
        if (bias) bv = *reinterpret_cast<const float4*>(&bias[n0 + tx * 4]);
        #pragma unroll
        for (int i = 0; i < 4; ++i) {
            int gm = m0 + ty * 4 + i;
            if (gm >= M) continue;
            float4 o;
            o.x = acc[i][0] + bv.x; o.y = acc[i][1] + bv.y;
            o.z = acc[i][2] + bv.z; o.w = acc[i][3] + bv.w;
            if (ACT) {
                o.x = o.x / (1.f + __expf(-o.x));
                o.y = o.y / (1.f + __expf(-o.y));
                o.z = o.z / (1.f + __expf(-o.z));
                o.w = o.w / (1.f + __expf(-o.w));
            }
            *reinterpret_cast<float4*>(&C[(long)zb * czs + (size_t)gm * ldc + n0 + tx * 4]) = o;
        }
    } else {
        #pragma unroll
        for (int i = 0; i < 4; ++i) {
            int gm = m0 + ty * 4 + i;
            if (gm >= M) continue;
            float4 o = make_float4(acc[i][0], acc[i][1], acc[i][2], acc[i][3]);
            *reinterpret_cast<float4*>(
                &Cpart[(((long)zb * KS + ks) * M + gm) * N + n0 + tx * 4]) = o;
        }
    }
}

// ---------------------------------------------------------------------------
// Split-K fixup: C = act( sum_ks Cpart + bias )
// ---------------------------------------------------------------------------
template <int ACT>
__global__ __launch_bounds__(256) void fix_kernel(
    const float* __restrict__ P, const float* __restrict__ bias,
    float* __restrict__ C, int M, int N, int ldc, long czs, int bzs,
    int KS, int Z) {

    int gid = blockIdx.x * 256 + threadIdx.x;
    int per_z = M * (N >> 2);
    if (gid >= Z * per_z) return;
    int zb = gid / per_z;
    int rem = gid - zb * per_z;
    int m = rem / (N >> 2);
    int n4 = (rem - m * (N >> 2)) << 2;

    float4 s = make_float4(0.f, 0.f, 0.f, 0.f);
    for (int ks = 0; ks < KS; ++ks) {
        float4 v = *reinterpret_cast<const float4*>(
            &P[(((long)zb * KS + ks) * M + m) * N + n4]);
        s.x += v.x; s.y += v.y; s.z += v.z; s.w += v.w;
    }
    if (bias) {
        float4 bv = *reinterpret_cast<const float4*>(&bias[zb * bzs + n4]);
        s.x += bv.x; s.y += bv.y; s.z += bv.z; s.w += bv.w;
    }
    if (ACT) {
        s.x = s.x / (1.f + __expf(-s.x));
        s.y = s.y / (1.f + __expf(-s.y));
        s.z = s.z / (1.f + __expf(-s.z));
        s.w = s.w / (1.f + __expf(-s.w));
    }
    *reinterpret_cast<float4*>(&C[(long)zb * czs + (long)m * ldc + n4]) = s;
}

// ---------------------------------------------------------------------------
// K2: flash-tiled attention, one block per (b,n). Tiles of LT=64 l-values;
// online softmax; pass2 re-reads the just-read tile (L3-hot).
// ---------------------------------------------------------------------------
__global__ __launch_bounds__(512, 4) void attn_kernel(const float* __restrict__ x,
                                                      const float* __restrict__ qk,
                                                      float* __restrict__ wkv) {
    int blk = blockIdx.x;
    int b = blk / N_, n = blk % N_;
    int t1 = n / T_, t2 = n % T_;
    const float* xb = x + (size_t)b * D_ * CHW + (size_t)(t1 * 16) * IMG + t2 * 16;
    const float* qkb = qk + (size_t)blk * (NH * D_);
    float* wkvb = wkv + (size_t)blk * (NH * D_);

    __shared__ float qk_s[NH * D_];      // 36 KB (reused as combine staging)
    __shared__ float pp[8][NH][LT];      // 24 KB
    __shared__ float p_s[NH][LT];        // 3 KB
    __shared__ float m_s[NH], s_s[NH], f_s[NH];

    int tid = threadIdx.x;
    int w = tid >> 6, lane = tid & 63;

    for (int i = tid; i < NH * D_ / 4; i += 512)
        reinterpret_cast<float4*>(qk_s)[i] = reinterpret_cast<const float4*>(qkb)[i];
    if (tid < NH) { m_s[tid] = -1e30f; s_s[tid] = 0.f; }

    // pass2 persistent state
    int hg = w & 3, r = w >> 2;
    int g1b = lane >> 2, g2b = lane & 3;
    float4 oacc[3][3];
    #pragma unroll
    for (int hh = 0; hh < 3; ++hh)
        #pragma unroll
        for (int co = 0; co < 3; ++co) oacc[hh][co] = make_float4(0.f, 0.f, 0.f, 0.f);

    __syncthreads();

    for (int t = 0; t < LL / LT; ++t) {
        // ---------------- pass1: scores for this tile ----------------
        int lg = t * LT + lane;
        float acc1[NH];
        #pragma unroll
        for (int h = 0; h < NH; ++h) acc1[h] = 0.f;

        #pragma unroll
        for (int j = 0; j < 6; ++j) {
            int p = w * 6 + j;
            int co = p >> 4, g1 = p & 15;
            const float* rowp = xb + (size_t)(3 * lg + co) * CHW + g1 * IMG;
            float4 k0 = *reinterpret_cast<const float4*>(rowp + 0);
            float4 k1 = *reinterpret_cast<const float4*>(rowp + 4);
            float4 k2 = *reinterpret_cast<const float4*>(rowp + 8);
            float4 k3 = *reinterpret_cast<const float4*>(rowp + 12);
            int base = co * 256 + g1 * 16;
            #pragma unroll
            for (int h = 0; h < NH; ++h) {
                const float4* q4 = reinterpret_cast<const float4*>(&qk_s[h * D_ + base]);
                float4 q0 = q4[0], q1 = q4[1], q2 = q4[2], q3 = q4[3];
                acc1[h] += q0.x * k0.x + q0.y * k0.y + q0.z * k0.z + q0.w * k0.w
                         + q1.x * k1.x + q1.y * k1.y + q1.z * k1.z + q1.w * k1.w
                         + q2.x * k2.x + q2.y * k2.y + q2.z * k2.z + q2.w * k2.w
                         + q3.x * k3.x + q3.y * k3.y + q3.z * k3.z + q3.w * k3.w;
            }
        }
        #pragma unroll
        for (int h = 0; h < NH; ++h) pp[w][h][lane] = acc1[h];
        __syncthreads();

        // ---------------- reduce + online softmax update ----------------
        for (int h = w; h < NH; h += 8) {
            float s = 0.f;
            #pragma unroll
            for (int ww = 0; ww < 8; ++ww) s += pp[ww][h][lane];
            s *= 0.125f;
            float mt = s;
            #pragma unroll
            for (int off = 32; off > 0; off >>= 1) mt = fmaxf(mt, __shfl_xor(mt, off));
            float m_old = m_s[h];
            float m_new = fmaxf(m_old, mt);
            float e = __expf(s - m_new);
            float sum = e;
            #pragma unroll
            for (int off = 32; off > 0; off >>= 1) sum += __shfl_xor(sum, off);
            p_s[h][lane] = e;
            if (lane == 0) {
                float f = __expf(m_old - m_new);
                f_s[h] = f;
                s_s[h] = s_s[h] * f + sum;
                m_s[h] = m_new;
            }
        }
        __syncthreads();

        // ---------------- pass2: rescale + accumulate ----------------
        float fr[3];
        fr[0] = f_s[hg * 3 + 0]; fr[1] = f_s[hg * 3 + 1]; fr[2] = f_s[hg * 3 + 2];
        #pragma unroll
        for (int hh = 0; hh < 3; ++hh)
            #pragma unroll
            for (int co = 0; co < 3; ++co) {
                oacc[hh][co].x *= fr[hh]; oacc[hh][co].y *= fr[hh];
                oacc[hh][co].z *= fr[hh]; oacc[hh][co].w *= fr[hh];
            }

        for (int lt = 0; lt < LT / 2; ++lt) {
            int l = r * (LT / 2) + lt;
            int lg2 = t * LT + l;
            const float* xl = xb + (size_t)(3 * lg2) * CHW + g1b * IMG + g2b * 4;
            float p0 = p_s[hg * 3 + 0][l];
            float p1 = p_s[hg * 3 + 1][l];
            float p2v = p_s[hg * 3 + 2][l];
            #pragma unroll
            for (int co = 0; co < 3; ++co) {
                float4 kv = *reinterpret_cast<const float4*>(xl + (size_t)co * CHW);
                oacc[0][co].x += p0 * kv.x;  oacc[0][co].y += p0 * kv.y;
                oacc[0][co].z += p0 * kv.z;  oacc[0][co].w += p0 * kv.w;
                oacc[1][co].x += p1 * kv.x;  oacc[1][co].y += p1 * kv.y;
                oacc[1][co].z += p1 * kv.z;  oacc[1][co].w += p1 * kv.w;
                oacc[2][co].x += p2v * kv.x; oacc[2][co].y += p2v * kv.y;
                oacc[2][co].z += p2v * kv.z; oacc[2][co].w += p2v * kv.w;
            }
        }
        __syncthreads();
    }

    // ---------------- epilogue: combine halves, normalize ----------------
    int slot = lane * 4;
    if (r == 0) {
        #pragma unroll
        for (int hh = 0; hh < 3; ++hh)
            #pragma unroll
            for (int co = 0; co < 3; ++co)
                *reinterpret_cast<float4*>(&qk_s[(hg * 3 + hh) * D_ + co * 256 + slot]) = oacc[hh][co];
    }
    __syncthreads();
    if (r == 1) {
        #pragma unroll
        for (int hh = 0; hh < 3; ++hh) {
            float inv = 1.0f / s_s[hg * 3 + hh];
            #pragma unroll
            for (int co = 0; co < 3; ++co) {
                float4 o = *reinterpret_cast<float4*>(&qk_s[(hg * 3 + hh) * D_ + co * 256 + slot]);
                float4 s;
                s.x = (oacc[hh][co].x + o.x) * inv;
                s.y = (oacc[hh][co].y + o.y) * inv;
                s.z = (oacc[hh][co].z + o.z) * inv;
                s.w = (oacc[hh][co].w + o.w) * inv;
                *reinterpret_cast<float4*>(&wkvb[(hg * 3 + hh) * D_ + co * 256 + slot]) = s;
            }
        }
    }
}

// ---------------------------------------------------------------------------
extern "C" void kernel_launch(void* const* d_in, const int* in_sizes, int n_in,
                              void* d_out, int out_size, void* d_ws, size_t ws_size,
                              hipStream_t stream) {
    const float* x     = (const float*)d_in[0];
    const float* w_in  = (const float*)d_in[1];
    const float* b_in  = (const float*)d_in[2];
    const float* w_out = (const float*)d_in[3];
    const float* b_out = (const float*)d_in[4];
    const float* w_fc1 = (const float*)d_in[5];
    const float* b_fc1 = (const float*)d_in[6];
    const float* w_fc2 = (const float*)d_in[7];
    const float* b_fc2 = (const float*)d_in[8];
    float* y = (float*)d_out;

    float* ws   = (float*)d_ws;
    float* q    = ws;                           // 784*768
    float* qp   = q    + (size_t)BN * D_;       // 784*768
    float* qkb  = qp   + (size_t)BN * D_;       // 784*9216
    float* wkv  = qkb  + (size_t)BN * NH * D_;  // 784*9216
    float* ctx  = wkv  + (size_t)BN * NH * D_;  // 784*768
    float* aout = ctx  + (size_t)BN * D_;       // 784*768
    float* h1   = aout + (size_t)BN * D_;       // 784*3072

    // split-K partial buffers alias dead regions:
    float* pb_h1  = h1;    // 784*3072 floats = 4*784*768  (used before h1 live)
    float* pb_qkb = qkb;   // 784*9216 floats >= 8*784*768 (used after attn)

    const float* wq = w_in;
    const float* wk = w_in + (size_t)D_ * D_;
    const float* wv = w_in + (size_t)2 * D_ * D_;
    const float* bq = b_in;
    const float* bv = b_in + 2 * D_;

    // K0: pooled q  (coalesced 896B rows)
    pool_kernel<<<dim3(B_ * T_ * 16), dim3(256), 0, stream>>>(x, q);

    // K1a: qp = q @ wq^T + bq   (split-K 4)
    gemm_kernel<1, 0><<<dim3(13, 12, 4), dim3(256), 0, stream>>>(
        q, wq, nullptr, nullptr, pb_h1, BN, D_, D_, D_, D_, D_, 0, 0, 0, 0, 4);
    fix_kernel<0><<<dim3(588), dim3(256), 0, stream>>>(
        pb_h1, bq, qp, BN, D_, D_, 0, 0, 4, 1);

    // K1b: per-head qk = qp_head @ wk_head   (K=64, direct)
    gemm_kernel<0, 0><<<dim3(13, 12, NH), dim3(256), 0, stream>>>(
        qp, wk, nullptr, qkb, nullptr, BN, D_, HD, D_, D_, NH * D_,
        (long)HD, (long)HD * D_, (long)D_, 0, 1);

    // K2: flash attention -> wkv
    attn_kernel<<<dim3(BN), dim3(512), 0, stream>>>(x, qkb, wkv);

    // K3a: per-head ctx = wkv_head @ wv_head^T + bv_head   (split-K 4, Z=12)
    gemm_kernel<1, 0><<<dim3(13, 1, NH * 4), dim3(256), 0, stream>>>(
        wkv, wv, nullptr, nullptr, pb_qkb, BN, HD, D_, NH * D_, D_, D_,
        (long)D_, (long)HD * D_, (long)HD, HD, 4);
    fix_kernel<0><<<dim3(588), dim3(256), 0, stream>>>(
        pb_qkb, bv, ctx, BN, HD, D_, (long)HD, HD, 4, NH);

    // K3b: aout = ctx @ w_out^T + b_out   (split-K 4)
    gemm_kernel<1, 0><<<dim3(13, 12, 4), dim3(256), 0, stream>>>(
        ctx, w_out, nullptr, nullptr, pb_qkb, BN, D_, D_, D_, D_, D_, 0, 0, 0, 0, 4);
    fix_kernel<0><<<dim3(588), dim3(256), 0, stream>>>(
        pb_qkb, b_out, aout, BN, D_, D_, 0, 0, 4, 1);

    // K4a: h1 = silu(aout @ w_fc1^T + b_fc1)   (direct, 624 blocks)
    gemm_kernel<1, 1><<<dim3(13, 48, 1), dim3(256), 0, stream>>>(
        aout, w_fc1, b_fc1, h1, nullptr, BN, FF_, D_, D_, D_, FF_, 0, 0, 0, 0, 1);

    // K4b: y = h1 @ w_fc2^T + b_fc2   (split-K 8)
    gemm_kernel<1, 0><<<dim3(13, 12, 8), dim3(256), 0, stream>>>(
        h1, w_fc2, nullptr, nullptr, pb_qkb, BN, D_, FF_, FF_, FF_, D_, 0, 0, 0, 0, 8);
    fix_kernel<0><<<dim3(588), dim3(256), 0, stream>>>(
        pb_qkb, b_fc2, y, BN, D_, D_, 0, 0, 8, 1);
}